// Round 18
// baseline (148.759 us; speedup 1.0000x reference)
//
#include <hip/hip_runtime.h>
#include <hip/hip_bf16.h>
#include <math.h>

// SpectralConv2d (FNO): B=16, Cin=Cout=32, H=W=256, MODES=16x16.
// kF redesigned: m-split waves (wave wv owns m=4wv..4wv+3 over ALL h) with
// staggered row windows (j0=wv*32) + depth-4 prefetch ring -> 64KB/CU HBM
// in flight (vs 16KB before; Little's law needs ~20KB at ~2000cyc latency).
// No cross-wave reduce needed; VGPR ~105 (no spills). kI = R8 verbatim.
//  kF (b,i): T[m][w] = sum_h x[h][w] e^{-2pi i m h/256} (radix-2 pairs),
//            P[m][p][w<128] = T[w] + (-1)^p T[w+128],
//            xsub[m][n] = sum_{w<128} P[m][n&1][w] e^{-2pi i n w/256}
//  kI (b,o): os = sum_i xsub*W; U via radix-2 over w; y = inverse h-DFT.

#define PI_F 3.14159265358979323846f

__global__ __launch_bounds__(256, 2) void kF(const float* __restrict__ x,
                                             float2* __restrict__ xsub) {
    __shared__ float2 tw[256];
    __shared__ float2 Ts[16][4][65];     // [m][c][l], w = 4l+c     33.3 KB
    __shared__ float2 P[16][2][129];     // parity planes           33.0 KB

    const int t = threadIdx.x;
    { float ang = (2.0f * PI_F / 256.0f) * (float)t;
      tw[t] = make_float2(__cosf(ang), __sinf(ang)); }
    __syncthreads();

    const int bi = blockIdx.x;
    const float4* xq = (const float4*)(x + (size_t)bi * 65536);  // row j -> xq[j*64+l]
    const int l = t & 63, wv = t >> 6;
    const int m0 = wv * 4;               // wave owns m0..m0+3
    const int j0 = wv * 32;              // staggered start row (disjoint streams)

    float Tr[4][4], Ti[4][4];            // [k][c]
#pragma unroll
    for (int k = 0; k < 4; ++k)
#pragma unroll
        for (int c = 0; c < 4; ++c) { Tr[k][c] = 0.0f; Ti[k][c] = 0.0f; }

    // 4 independent twiddle chains W_k = e^{-2pi i (m0+k) h/256}
    float Wr[4], Wi[4], Sr[4], Si[4];
#pragma unroll
    for (int k = 0; k < 4; ++k) {
        float2 i0 = tw[((m0 + k) * j0) & 255];
        Wr[k] = i0.x; Wi[k] = -i0.y;     // e^{-i a}
        float2 st = tw[m0 + k];
        Sr[k] = st.x; Si[k] = -st.y;     // step e^{-2pi i (m0+k)/256}
    }
    const int wrapJJ = 128 - j0;         // physical row wraps 127->0 here (wv>0)

    // depth-4 prefetch ring (statically indexed under unroll 4)
    float4 va[4], vb[4];
#pragma unroll
    for (int p = 0; p < 4; ++p) {
        int j = (j0 + p) & 127;
        va[p] = xq[j * 64 + l];
        vb[p] = xq[(j + 128) * 64 + l];
    }

#pragma unroll 4
    for (int jj = 0; jj < 128; ++jj) {
        if (jj == wrapJJ) {              // wave-uniform; chain off by (-1)^{m0+k} = (-1)^k
#pragma unroll
            for (int k = 1; k < 4; k += 2) { Wr[k] = -Wr[k]; Wi[k] = -Wi[k]; }
        }
        const int slot = jj & 3;
        const float4 v0 = va[slot], v1 = vb[slot];
        const int jn = (j0 + jj + 4) & 127;
        va[slot] = xq[jn * 64 + l];      // issue next loads immediately
        vb[slot] = xq[(jn + 128) * 64 + l];

        const float xe[4] = {v0.x + v1.x, v0.y + v1.y, v0.z + v1.z, v0.w + v1.w};
        const float xo[4] = {v0.x - v1.x, v0.y - v1.y, v0.z - v1.z, v0.w - v1.w};
#pragma unroll
        for (int k = 0; k < 4; ++k) {
            const float wr = Wr[k], wi2 = Wi[k];
#pragma unroll
            for (int c = 0; c < 4; ++c) {
                const float xv = (k & 1) ? xo[c] : xe[c];   // parity(m0+k)=k&1 (m0 even)
                Tr[k][c] = fmaf(xv, wr, Tr[k][c]);
                Ti[k][c] = fmaf(xv, wi2, Ti[k][c]);
            }
            const float nr = fmaf(wr, Sr[k], -wi2 * Si[k]); // W *= S
            Wi[k] = fmaf(wr, Si[k], wi2 * Sr[k]);
            Wr[k] = nr;
        }
    }

    // each wave writes its own Ts rows (disjoint) — no reduce phase
#pragma unroll
    for (int k = 0; k < 4; ++k)
#pragma unroll
        for (int c = 0; c < 4; ++c)
            Ts[m0 + k][c][l] = make_float2(Tr[k][c], Ti[k][c]);
    __syncthreads();

    // parity precombine: P[m][p][w] = T[m][w] + (-1)^p T[m][w+128], w<128
#pragma unroll
    for (int k = 0; k < 8; ++k) {
        const int s = k * 256 + t;       // 16m x 128w slots
        const int m = s >> 7, w = s & 127;
        const int c = w & 3, li = w >> 2;
        float2 A = Ts[m][c][li], Bv = Ts[m][c][li + 32];
        P[m][0][w] = make_float2(A.x + Bv.x, A.y + Bv.y);
        P[m][1][w] = make_float2(A.x - Bv.x, A.y - Bv.y);
    }
    __syncthreads();

    // w-DFT tail: thread (m = t>>4, n = t&15), 128 iters on parity plane
    const int m = t >> 4, n = t & 15;
    const float2* Pp = &P[m][n & 1][0];
    float ang = (2.0f * PI_F / 256.0f) * (float)n;
    float c1 = __cosf(ang), s1 = __sinf(ang);
    float cr = 1.0f, ci = 0.0f;
    float ar = 0.0f, ai = 0.0f;
    for (int w = 0; w < 128; ++w) {
        float2 Tv = Pp[w];               // 8 distinct banks/wave, broadcast
        ar += Tv.x * cr + Tv.y * ci;     // * e^{-i n w}
        ai += Tv.y * cr - Tv.x * ci;
        float nr = fmaf(cr, c1, -ci * s1);
        float nc = fmaf(cr, s1, ci * c1);
        cr = nr; ci = nc;
    }
    xsub[(size_t)bi * 256 + t] = make_float2(ar, ai);
}

__global__ __launch_bounds__(256, 2) void kI(const float2* __restrict__ xsub,
                                             const float* __restrict__ wr,
                                             const float* __restrict__ wi,
                                             float* __restrict__ y) {
    __shared__ float2 tw[256];
    __shared__ float2 os[256];
    __shared__ float2 U[16][256];        // 32 KB
    const int t = threadIdx.x;
    { float ang = (2.0f * PI_F / 256.0f) * (float)t;
      tw[t] = make_float2(__cosf(ang), __sinf(ang)); }

    const int bo = blockIdx.x, b = bo >> 5, o = bo & 31;

    // stage 1: channel mix over Cin
    {
        float ar = 0.0f, ai = 0.0f;
#pragma unroll 8
        for (int i = 0; i < 32; ++i) {
            float2 xv = xsub[(size_t)(b * 32 + i) * 256 + t];
            float wre = wr[(size_t)(i * 32 + o) * 256 + t];
            float wim = wi[(size_t)(i * 32 + o) * 256 + t];
            ar += xv.x * wre - xv.y * wim;
            ai += xv.x * wim + xv.y * wre;
        }
        os[t] = make_float2(ar, ai);
    }
    __syncthreads();

    // stage 2: radix-2 over w: thread (mh = t>>7, w0 = t&127) fills
    // U[m][w0] and U[m][w0+128] from one os*tw product ((-1)^n sign)
    {
        const int w0 = t & 127, mh = t >> 7;
        float twr[16], twi[16];
#pragma unroll
        for (int n = 0; n < 16; ++n) {
            float2 cs = tw[(n * w0) & 255];
            twr[n] = cs.x; twi[n] = cs.y;
        }
#pragma unroll
        for (int mm = 0; mm < 8; ++mm) {
            const int m = mh * 8 + mm;
            float u0r = 0.f, u0i = 0.f, u1r = 0.f, u1i = 0.f;
#pragma unroll
            for (int n = 0; n < 16; ++n) {
                float2 ov = os[m * 16 + n];          // uniform -> broadcast
                float tr = ov.x * twr[n] - ov.y * twi[n];   // * e^{+i n w0}
                float ti2 = ov.x * twi[n] + ov.y * twr[n];
                u0r += tr; u0i += ti2;
                if (n & 1) { u1r -= tr; u1i -= ti2; }
                else       { u1r += tr; u1i += ti2; }
            }
            U[m][w0]       = make_float2(u0r, u0i);
            U[m][w0 + 128] = make_float2(u1r, u1i);
        }
    }
    __syncthreads();

    // stage 3: inverse h-DFT (radix-2 over h), lane owns w = 4l..4l+3
    const int l = t & 63, wv = t >> 6;
    const int h0 = wv * 32;
    float Ur[4][16], Ui[4][16];
#pragma unroll
    for (int m = 0; m < 16; ++m) {
        const float4* Um = (const float4*)&U[m][0];
        float4 p0 = Um[2 * l], p1 = Um[2 * l + 1];
        Ur[0][m] = p0.x; Ui[0][m] = p0.y; Ur[1][m] = p0.z; Ui[1][m] = p0.w;
        Ur[2][m] = p1.x; Ui[2][m] = p1.y; Ur[3][m] = p1.z; Ui[3][m] = p1.w;
    }
    float Rr[16], Ri[16], Sr[16], Si[16];
#pragma unroll
    for (int m = 0; m < 16; ++m) {
        float2 i0 = tw[(m * h0) & 255];
        Rr[m] = i0.x; Ri[m] = i0.y;      // e^{+i m h0}
        float2 st = tw[m];
        Sr[m] = st.x;                    // e^{+i m}
        Si[m] = st.y;
    }

    float* yp = y + (size_t)bo * 65536;
    const float inv = 1.0f / 65536.0f;
#pragma unroll 2
    for (int j = 0; j < 32; ++j) {
        const int h = h0 + j;            // h-pair (h, h+128)
        float ae[4] = {0, 0, 0, 0}, ao[4] = {0, 0, 0, 0};
#pragma unroll
        for (int m = 0; m < 16; ++m) {
            const float cr = Rr[m], ci = Ri[m];
#pragma unroll
            for (int c = 0; c < 4; ++c) {
                float v = fmaf(Ur[c][m], cr, -(Ui[c][m] * ci)); // Re(U e^{+ia})
                if (m & 1) ao[c] += v; else ae[c] += v;
            }
            Rr[m] = fmaf(cr, Sr[m], -ci * Si[m]);     // R *= S
            Ri[m] = fmaf(cr, Si[m],  ci * Sr[m]);
        }
        float4 ye, yo2;
        ye.x = (ae[0] + ao[0]) * inv; ye.y = (ae[1] + ao[1]) * inv;
        ye.z = (ae[2] + ao[2]) * inv; ye.w = (ae[3] + ao[3]) * inv;
        yo2.x = (ae[0] - ao[0]) * inv; yo2.y = (ae[1] - ao[1]) * inv;
        yo2.z = (ae[2] - ao[2]) * inv; yo2.w = (ae[3] - ao[3]) * inv;
        ((float4*)(yp + h * 256))[l] = ye;
        ((float4*)(yp + (h + 128) * 256))[l] = yo2;
    }
}

extern "C" void kernel_launch(void* const* d_in, const int* in_sizes, int n_in,
                              void* d_out, int out_size, void* d_ws, size_t ws_size,
                              hipStream_t stream) {
    const float* x  = (const float*)d_in[0];   // [16][32][256][256]
    const float* wr = (const float*)d_in[1];   // [32][32][16][16]
    const float* wi = (const float*)d_in[2];   // [32][32][16][16]
    float* y = (float*)d_out;                  // [16][32][256][256]

    float2* xsub = (float2*)d_ws;              // 512*256*8 = 1 MB

    kF<<<512, 256, 0, stream>>>(x, xsub);
    kI<<<512, 256, 0, stream>>>(xsub, wr, wi, y);
}

// Round 19
// 72.578 us; speedup vs baseline: 2.0496x; 2.0496x over previous
//
#include <hip/hip_runtime.h>
#include <hip/hip_bf16.h>
#include <math.h>

// SpectralConv2d (FNO): B=16, Cin=Cout=32, H=W=256, MODES=16x16.
// R8 structure (best: 73.3us) with VALU cuts at constant structure:
//  - kF main loop radix-4 over h (i^m -> real/imag swaps): -32% VALU
//  - kI stage-3 fused 2-FMA accumulation: -25% VALU
//  kF (b,i): T[m][w] = sum_h x[h][w] e^{-2pi i m h/256},
//            P[m][p][w<128] = T[w] + (-1)^p T[w+128],
//            xsub[m][n] = sum_{w<128} P[m][n&1][w] e^{-2pi i n w/256}
//  kI (b,o): os = sum_i xsub*W; U via radix-2 over w; y = inverse h-DFT.

#define PI_F 3.14159265358979323846f

__global__ __launch_bounds__(256, 2) void kF(const float* __restrict__ x,
                                             float2* __restrict__ xsub) {
    __shared__ float2 tw[256];
    __shared__ float2 Ts[16][4][65];     // [m][c][l], w = 4l+c, padded  33.3 KB
    __shared__ float2 redP[4128];        // union: red[4][4][4][64] / P[16][2][129]
    auto red = reinterpret_cast<float2 (*)[4][4][64]>(redP);
    auto P   = reinterpret_cast<float2 (*)[2][129]>(redP);

    const int t = threadIdx.x;
    { float ang = (2.0f * PI_F / 256.0f) * (float)t;
      tw[t] = make_float2(__cosf(ang), __sinf(ang)); }
    __syncthreads();

    const int bi = blockIdx.x;
    const float4* xq = (const float4*)(x + (size_t)bi * 65536);  // row r -> xq[r*64+l]
    const int l = t & 63, wv = t >> 6;
    const int h0 = wv * 16;              // wave covers h0..h0+15 (x4 rows each)

    float Tr[4][16], Ti[4][16];          // [c][m]
#pragma unroll
    for (int c = 0; c < 4; ++c)
#pragma unroll
        for (int m = 0; m < 16; ++m) { Tr[c][m] = 0.0f; Ti[c][m] = 0.0f; }

    // rotators W_m = e^{-2pi i m h/256}, step S_m = e^{-2pi i m/256}
    float Wr[16], Wi[16], Sr[16], Si[16];
#pragma unroll
    for (int m = 0; m < 16; ++m) {
        float2 i0 = tw[(m * h0) & 255];
        Wr[m] = i0.x; Wi[m] = -i0.y;
        float2 st = tw[m];
        Sr[m] = st.x; Si[m] = -st.y;
    }

    // radix-4 over h: rows h, h+64, h+128, h+192; i^m -> class tricks
    for (int j = 0; j < 16; ++j) {
        const int h = h0 + j;
        const float4 v0 = xq[h * 64 + l];
        const float4 v1 = xq[(h + 64) * 64 + l];
        const float4 v2 = xq[(h + 128) * 64 + l];
        const float4 v3 = xq[(h + 192) * 64 + l];
        const float a[4]  = {v0.x + v2.x, v0.y + v2.y, v0.z + v2.z, v0.w + v2.w};
        const float bb[4] = {v0.x - v2.x, v0.y - v2.y, v0.z - v2.z, v0.w - v2.w};
        const float cc[4] = {v1.x + v3.x, v1.y + v3.y, v1.z + v3.z, v1.w + v3.w};
        const float d[4]  = {v1.x - v3.x, v1.y - v3.y, v1.z - v3.z, v1.w - v3.w};
        float se0[4], se2[4];
#pragma unroll
        for (int c = 0; c < 4; ++c) { se0[c] = a[c] + cc[c]; se2[c] = a[c] - cc[c]; }

#pragma unroll
        for (int m = 0; m < 16; ++m) {
            const float wr = Wr[m], wi2 = Wi[m];
            if ((m & 3) == 0) {
#pragma unroll
                for (int c = 0; c < 4; ++c) {
                    Tr[c][m] = fmaf(se0[c], wr,  Tr[c][m]);
                    Ti[c][m] = fmaf(se0[c], wi2, Ti[c][m]);
                }
            } else if ((m & 3) == 2) {
#pragma unroll
                for (int c = 0; c < 4; ++c) {
                    Tr[c][m] = fmaf(se2[c], wr,  Tr[c][m]);
                    Ti[c][m] = fmaf(se2[c], wi2, Ti[c][m]);
                }
            } else if ((m & 3) == 1) {   // s = b - i d: T += (b - i d) * W
#pragma unroll
                for (int c = 0; c < 4; ++c) {
                    Tr[c][m] = fmaf(bb[c], wr,  Tr[c][m]);
                    Tr[c][m] = fmaf(d[c],  wi2, Tr[c][m]);
                    Ti[c][m] = fmaf(bb[c], wi2, Ti[c][m]);
                    Ti[c][m] = fmaf(-d[c], wr,  Ti[c][m]);
                }
            } else {                     // s = b + i d
#pragma unroll
                for (int c = 0; c < 4; ++c) {
                    Tr[c][m] = fmaf(bb[c], wr,  Tr[c][m]);
                    Tr[c][m] = fmaf(-d[c], wi2, Tr[c][m]);
                    Ti[c][m] = fmaf(bb[c], wi2, Ti[c][m]);
                    Ti[c][m] = fmaf(d[c],  wr,  Ti[c][m]);
                }
            }
            const float nr = fmaf(wr, Sr[m], -wi2 * Si[m]);  // W *= S
            Wi[m] = fmaf(wr, Si[m], wi2 * Sr[m]);
            Wr[m] = nr;
        }
    }

    // cross-wave reduce into Ts, 4 m-groups of 4
#pragma unroll
    for (int mg = 0; mg < 4; ++mg) {
        if (mg) __syncthreads();
#pragma unroll
        for (int mm = 0; mm < 4; ++mm)
#pragma unroll
            for (int c = 0; c < 4; ++c)
                red[wv][mm][c][l] = make_float2(Tr[c][mg * 4 + mm], Ti[c][mg * 4 + mm]);
        __syncthreads();
        const int mq = t >> 6, idx = t & 63;
#pragma unroll
        for (int c = 0; c < 4; ++c) {
            float2 a0 = red[0][mq][c][idx], a1 = red[1][mq][c][idx];
            float2 a2 = red[2][mq][c][idx], a3 = red[3][mq][c][idx];
            Ts[mg * 4 + mq][c][idx] =
                make_float2(a0.x + a1.x + a2.x + a3.x, a0.y + a1.y + a2.y + a3.y);
        }
    }
    __syncthreads();                      // red no longer live; P may overwrite

    // parity precombine: P[m][p][w] = T[m][w] + (-1)^p T[m][w+128], w<128
#pragma unroll
    for (int k = 0; k < 8; ++k) {
        const int s = k * 256 + t;        // 16m x 128w slots
        const int m = s >> 7, w = s & 127;
        const int c = w & 3, li = w >> 2;
        float2 A = Ts[m][c][li], Bv = Ts[m][c][li + 32];
        P[m][0][w] = make_float2(A.x + Bv.x, A.y + Bv.y);
        P[m][1][w] = make_float2(A.x - Bv.x, A.y - Bv.y);
    }
    __syncthreads();

    // w-DFT tail: thread (m = t>>4, n = t&15), 128 iters on parity plane
    const int m = t >> 4, n = t & 15;
    const float2* Pp = &P[m][n & 1][0];
    float ang = (2.0f * PI_F / 256.0f) * (float)n;
    float c1 = __cosf(ang), s1 = __sinf(ang);
    float cr = 1.0f, ci = 0.0f;
    float ar = 0.0f, ai = 0.0f;
    for (int w = 0; w < 128; ++w) {
        float2 Tv = Pp[w];               // 8 distinct banks/wave, broadcast
        ar += Tv.x * cr + Tv.y * ci;     // * e^{-i n w}
        ai += Tv.y * cr - Tv.x * ci;
        float nr = fmaf(cr, c1, -ci * s1);
        float nc = fmaf(cr, s1, ci * c1);
        cr = nr; ci = nc;
    }
    xsub[(size_t)bi * 256 + t] = make_float2(ar, ai);
}

__global__ __launch_bounds__(256, 2) void kI(const float2* __restrict__ xsub,
                                             const float* __restrict__ wr,
                                             const float* __restrict__ wi,
                                             float* __restrict__ y) {
    __shared__ float2 tw[256];
    __shared__ float2 os[256];
    __shared__ float2 U[16][256];        // 32 KB
    const int t = threadIdx.x;
    { float ang = (2.0f * PI_F / 256.0f) * (float)t;
      tw[t] = make_float2(__cosf(ang), __sinf(ang)); }

    const int bo = blockIdx.x, b = bo >> 5, o = bo & 31;

    // stage 1: channel mix over Cin
    {
        float ar = 0.0f, ai = 0.0f;
#pragma unroll 8
        for (int i = 0; i < 32; ++i) {
            float2 xv = xsub[(size_t)(b * 32 + i) * 256 + t];
            float wre = wr[(size_t)(i * 32 + o) * 256 + t];
            float wim = wi[(size_t)(i * 32 + o) * 256 + t];
            ar += xv.x * wre - xv.y * wim;
            ai += xv.x * wim + xv.y * wre;
        }
        os[t] = make_float2(ar, ai);
    }
    __syncthreads();

    // stage 2: radix-2 over w: thread (mh = t>>7, w0 = t&127) fills
    // U[m][w0] and U[m][w0+128] from one os*tw product ((-1)^n sign)
    {
        const int w0 = t & 127, mh = t >> 7;
        float twr[16], twi[16];
#pragma unroll
        for (int n = 0; n < 16; ++n) {
            float2 cs = tw[(n * w0) & 255];
            twr[n] = cs.x; twi[n] = cs.y;
        }
#pragma unroll
        for (int mm = 0; mm < 8; ++mm) {
            const int m = mh * 8 + mm;
            float u0r = 0.f, u0i = 0.f, u1r = 0.f, u1i = 0.f;
#pragma unroll
            for (int n = 0; n < 16; ++n) {
                float2 ov = os[m * 16 + n];          // uniform -> broadcast
                float tr = ov.x * twr[n] - ov.y * twi[n];   // * e^{+i n w0}
                float ti2 = ov.x * twi[n] + ov.y * twr[n];
                u0r += tr; u0i += ti2;
                if (n & 1) { u1r -= tr; u1i -= ti2; }
                else       { u1r += tr; u1i += ti2; }
            }
            U[m][w0]       = make_float2(u0r, u0i);
            U[m][w0 + 128] = make_float2(u1r, u1i);
        }
    }
    __syncthreads();

    // stage 3: inverse h-DFT (radix-2 over h), lane owns w = 4l..4l+3;
    // fused 2-FMA accumulation (no separate v + add)
    const int l = t & 63, wv = t >> 6;
    const int h0 = wv * 32;
    float Ur[4][16], Ui[4][16];
#pragma unroll
    for (int m = 0; m < 16; ++m) {
        const float4* Um = (const float4*)&U[m][0];
        float4 p0 = Um[2 * l], p1 = Um[2 * l + 1];
        Ur[0][m] = p0.x; Ui[0][m] = p0.y; Ur[1][m] = p0.z; Ui[1][m] = p0.w;
        Ur[2][m] = p1.x; Ui[2][m] = p1.y; Ur[3][m] = p1.z; Ui[3][m] = p1.w;
    }
    float Rr[16], Ri[16], Sr[16], Si[16];
#pragma unroll
    for (int m = 0; m < 16; ++m) {
        float2 i0 = tw[(m * h0) & 255];
        Rr[m] = i0.x; Ri[m] = i0.y;      // e^{+i m h0}
        float2 st = tw[m];
        Sr[m] = st.x;                    // e^{+i m}
        Si[m] = st.y;
    }

    float* yp = y + (size_t)bo * 65536;
    const float inv = 1.0f / 65536.0f;
#pragma unroll 2
    for (int j = 0; j < 32; ++j) {
        float ae[4] = {0, 0, 0, 0}, ao[4] = {0, 0, 0, 0};
#pragma unroll
        for (int m = 0; m < 16; ++m) {
            const float cr = Rr[m], ci = Ri[m];
            if (m & 1) {
#pragma unroll
                for (int c = 0; c < 4; ++c) {
                    ao[c] = fmaf(Ur[c][m], cr, ao[c]);   // += Re(U e^{+ia})
                    ao[c] = fmaf(-Ui[c][m], ci, ao[c]);
                }
            } else {
#pragma unroll
                for (int c = 0; c < 4; ++c) {
                    ae[c] = fmaf(Ur[c][m], cr, ae[c]);
                    ae[c] = fmaf(-Ui[c][m], ci, ae[c]);
                }
            }
            Rr[m] = fmaf(cr, Sr[m], -ci * Si[m]);     // R *= S
            Ri[m] = fmaf(cr, Si[m],  ci * Sr[m]);
        }
        const int h = h0 + j;            // h-pair (h, h+128)
        float4 ye, yo2;
        ye.x = (ae[0] + ao[0]) * inv; ye.y = (ae[1] + ao[1]) * inv;
        ye.z = (ae[2] + ao[2]) * inv; ye.w = (ae[3] + ao[3]) * inv;
        yo2.x = (ae[0] - ao[0]) * inv; yo2.y = (ae[1] - ao[1]) * inv;
        yo2.z = (ae[2] - ao[2]) * inv; yo2.w = (ae[3] - ao[3]) * inv;
        ((float4*)(yp + h * 256))[l] = ye;
        ((float4*)(yp + (h + 128) * 256))[l] = yo2;
    }
}

extern "C" void kernel_launch(void* const* d_in, const int* in_sizes, int n_in,
                              void* d_out, int out_size, void* d_ws, size_t ws_size,
                              hipStream_t stream) {
    const float* x  = (const float*)d_in[0];   // [16][32][256][256]
    const float* wr = (const float*)d_in[1];   // [32][32][16][16]
    const float* wi = (const float*)d_in[2];   // [32][32][16][16]
    float* y = (float*)d_out;                  // [16][32][256][256]

    float2* xsub = (float2*)d_ws;              // 512*256*8 = 1 MB

    kF<<<512, 256, 0, stream>>>(x, xsub);
    kI<<<512, 256, 0, stream>>>(xsub, wr, wi, y);
}

// Round 20
// 70.362 us; speedup vs baseline: 2.1142x; 1.0315x over previous
//
#include <hip/hip_runtime.h>
#include <hip/hip_bf16.h>
#include <math.h>

// SpectralConv2d (FNO): B=16, Cin=Cout=32, H=W=256, MODES=16x16.
// R19 structure (72.6us) + two serial-phase cuts:
//  - kF tail: second radix step over w (+64 alias, (-i)^n twist) -> 64-iter tail
//  - kI stage-3: radix-4 over h (i^{mk} class accumulators) -> -27% VALU
//  kF (b,i): T[m][w] = sum_h x[h][w] e^{-2pi i m h/256} (radix-4 main loop),
//            P[m][n&1][w<128] (+128 parity), Q[m][n&3][w<64] (+64 twist),
//            xsub[m][n] = sum_{w<64} Q[m][n&3][w] e^{-2pi i n w/256}
//  kI (b,o): os = sum_i xsub*W; U via radix-2 over w; y = radix-4 inverse h-DFT.

#define PI_F 3.14159265358979323846f

__global__ __launch_bounds__(256, 2) void kF(const float* __restrict__ x,
                                             float2* __restrict__ xsub) {
    __shared__ float2 tw[256];
    __shared__ float2 Ts[16][4][65];     // [m][c][l]; later overlaid by Q[16][4][65]
    __shared__ float2 redP[4128];        // union: red[4][4][4][64] / P[16][2][129]
    auto red = reinterpret_cast<float2 (*)[4][4][64]>(redP);
    auto P   = reinterpret_cast<float2 (*)[2][129]>(redP);
    auto Q   = reinterpret_cast<float2 (*)[4][65]>(&Ts[0][0][0]);   // [16][4][65]

    const int t = threadIdx.x;
    { float ang = (2.0f * PI_F / 256.0f) * (float)t;
      tw[t] = make_float2(__cosf(ang), __sinf(ang)); }
    __syncthreads();

    const int bi = blockIdx.x;
    const float4* xq = (const float4*)(x + (size_t)bi * 65536);  // row r -> xq[r*64+l]
    const int l = t & 63, wv = t >> 6;
    const int h0 = wv * 16;              // wave covers h0..h0+15 (x4 rows each)

    float Tr[4][16], Ti[4][16];          // [c][m]
#pragma unroll
    for (int c = 0; c < 4; ++c)
#pragma unroll
        for (int m = 0; m < 16; ++m) { Tr[c][m] = 0.0f; Ti[c][m] = 0.0f; }

    // rotators W_m = e^{-2pi i m h/256}, step S_m = e^{-2pi i m/256}
    float Wr[16], Wi[16], Sr[16], Si[16];
#pragma unroll
    for (int m = 0; m < 16; ++m) {
        float2 i0 = tw[(m * h0) & 255];
        Wr[m] = i0.x; Wi[m] = -i0.y;
        float2 st = tw[m];
        Sr[m] = st.x; Si[m] = -st.y;
    }

    // radix-4 over h: rows h, h+64, h+128, h+192; i^m -> class tricks
    for (int j = 0; j < 16; ++j) {
        const int h = h0 + j;
        const float4 v0 = xq[h * 64 + l];
        const float4 v1 = xq[(h + 64) * 64 + l];
        const float4 v2 = xq[(h + 128) * 64 + l];
        const float4 v3 = xq[(h + 192) * 64 + l];
        const float a[4]  = {v0.x + v2.x, v0.y + v2.y, v0.z + v2.z, v0.w + v2.w};
        const float bb[4] = {v0.x - v2.x, v0.y - v2.y, v0.z - v2.z, v0.w - v2.w};
        const float cc[4] = {v1.x + v3.x, v1.y + v3.y, v1.z + v3.z, v1.w + v3.w};
        const float d[4]  = {v1.x - v3.x, v1.y - v3.y, v1.z - v3.z, v1.w - v3.w};
        float se0[4], se2[4];
#pragma unroll
        for (int c = 0; c < 4; ++c) { se0[c] = a[c] + cc[c]; se2[c] = a[c] - cc[c]; }

#pragma unroll
        for (int m = 0; m < 16; ++m) {
            const float wr = Wr[m], wi2 = Wi[m];
            if ((m & 3) == 0) {
#pragma unroll
                for (int c = 0; c < 4; ++c) {
                    Tr[c][m] = fmaf(se0[c], wr,  Tr[c][m]);
                    Ti[c][m] = fmaf(se0[c], wi2, Ti[c][m]);
                }
            } else if ((m & 3) == 2) {
#pragma unroll
                for (int c = 0; c < 4; ++c) {
                    Tr[c][m] = fmaf(se2[c], wr,  Tr[c][m]);
                    Ti[c][m] = fmaf(se2[c], wi2, Ti[c][m]);
                }
            } else if ((m & 3) == 1) {   // s = b - i d
#pragma unroll
                for (int c = 0; c < 4; ++c) {
                    Tr[c][m] = fmaf(bb[c], wr,  Tr[c][m]);
                    Tr[c][m] = fmaf(d[c],  wi2, Tr[c][m]);
                    Ti[c][m] = fmaf(bb[c], wi2, Ti[c][m]);
                    Ti[c][m] = fmaf(-d[c], wr,  Ti[c][m]);
                }
            } else {                     // s = b + i d
#pragma unroll
                for (int c = 0; c < 4; ++c) {
                    Tr[c][m] = fmaf(bb[c], wr,  Tr[c][m]);
                    Tr[c][m] = fmaf(-d[c], wi2, Tr[c][m]);
                    Ti[c][m] = fmaf(bb[c], wi2, Ti[c][m]);
                    Ti[c][m] = fmaf(d[c],  wr,  Ti[c][m]);
                }
            }
            const float nr = fmaf(wr, Sr[m], -wi2 * Si[m]);  // W *= S
            Wi[m] = fmaf(wr, Si[m], wi2 * Sr[m]);
            Wr[m] = nr;
        }
    }

    // cross-wave reduce into Ts, 4 m-groups of 4
#pragma unroll
    for (int mg = 0; mg < 4; ++mg) {
        if (mg) __syncthreads();
#pragma unroll
        for (int mm = 0; mm < 4; ++mm)
#pragma unroll
            for (int c = 0; c < 4; ++c)
                red[wv][mm][c][l] = make_float2(Tr[c][mg * 4 + mm], Ti[c][mg * 4 + mm]);
        __syncthreads();
        const int mq = t >> 6, idx = t & 63;
#pragma unroll
        for (int c = 0; c < 4; ++c) {
            float2 a0 = red[0][mq][c][idx], a1 = red[1][mq][c][idx];
            float2 a2 = red[2][mq][c][idx], a3 = red[3][mq][c][idx];
            Ts[mg * 4 + mq][c][idx] =
                make_float2(a0.x + a1.x + a2.x + a3.x, a0.y + a1.y + a2.y + a3.y);
        }
    }
    __syncthreads();                      // red dead; P may overwrite

    // parity precombine: P[m][p][w] = T[m][w] + (-1)^p T[m][w+128], w<128
#pragma unroll
    for (int k = 0; k < 8; ++k) {
        const int s = k * 256 + t;        // 16m x 128w slots
        const int m = s >> 7, w = s & 127;
        const int c = w & 3, li = w >> 2;
        float2 A = Ts[m][c][li], Bv = Ts[m][c][li + 32];
        P[m][0][w] = make_float2(A.x + Bv.x, A.y + Bv.y);
        P[m][1][w] = make_float2(A.x - Bv.x, A.y - Bv.y);
    }
    __syncthreads();                      // Ts dead; Q may overwrite

    // quarter planes: Q[m][n&3][w<64] = P[m][n&1][w] + (-i)^n P[m][n&1][w+64]
#pragma unroll
    for (int k = 0; k < 4; ++k) {
        const int s = k * 256 + t;        // 16m x 64w tasks
        const int m = s >> 6, w = s & 63;
        float2 a0 = P[m][0][w], b0 = P[m][0][w + 64];
        float2 a1 = P[m][1][w], b1 = P[m][1][w + 64];
        Q[m][0][w] = make_float2(a0.x + b0.x, a0.y + b0.y);
        Q[m][2][w] = make_float2(a0.x - b0.x, a0.y - b0.y);
        Q[m][1][w] = make_float2(a1.x + b1.y, a1.y - b1.x);   // + (-i)*b1
        Q[m][3][w] = make_float2(a1.x - b1.y, a1.y + b1.x);   // + (+i)*b1
    }
    __syncthreads();

    // w-DFT tail: thread (m = t>>4, n = t&15), 64 iters on quarter plane
    const int m = t >> 4, n = t & 15;
    const float2* Qp = &Q[m][n & 3][0];   // 16 distinct banks/wave, broadcast x4
    float ang = (2.0f * PI_F / 256.0f) * (float)n;
    float c1 = __cosf(ang), s1 = __sinf(ang);
    float cr = 1.0f, ci = 0.0f;
    float ar = 0.0f, ai = 0.0f;
    for (int w = 0; w < 64; ++w) {
        float2 Tv = Qp[w];
        ar += Tv.x * cr + Tv.y * ci;     // * e^{-i n w}
        ai += Tv.y * cr - Tv.x * ci;
        float nr = fmaf(cr, c1, -ci * s1);
        float nc = fmaf(cr, s1, ci * c1);
        cr = nr; ci = nc;
    }
    xsub[(size_t)bi * 256 + t] = make_float2(ar, ai);
}

__global__ __launch_bounds__(256, 2) void kI(const float2* __restrict__ xsub,
                                             const float* __restrict__ wr,
                                             const float* __restrict__ wi,
                                             float* __restrict__ y) {
    __shared__ float2 tw[256];
    __shared__ float2 os[256];
    __shared__ float2 U[16][256];        // 32 KB
    const int t = threadIdx.x;
    { float ang = (2.0f * PI_F / 256.0f) * (float)t;
      tw[t] = make_float2(__cosf(ang), __sinf(ang)); }

    const int bo = blockIdx.x, b = bo >> 5, o = bo & 31;

    // stage 1: channel mix over Cin
    {
        float ar = 0.0f, ai = 0.0f;
#pragma unroll 8
        for (int i = 0; i < 32; ++i) {
            float2 xv = xsub[(size_t)(b * 32 + i) * 256 + t];
            float wre = wr[(size_t)(i * 32 + o) * 256 + t];
            float wim = wi[(size_t)(i * 32 + o) * 256 + t];
            ar += xv.x * wre - xv.y * wim;
            ai += xv.x * wim + xv.y * wre;
        }
        os[t] = make_float2(ar, ai);
    }
    __syncthreads();

    // stage 2: radix-2 over w fills U[m][w0], U[m][w0+128]
    {
        const int w0 = t & 127, mh = t >> 7;
        float twr[16], twi[16];
#pragma unroll
        for (int n = 0; n < 16; ++n) {
            float2 cs = tw[(n * w0) & 255];
            twr[n] = cs.x; twi[n] = cs.y;
        }
#pragma unroll
        for (int mm = 0; mm < 8; ++mm) {
            const int m = mh * 8 + mm;
            float u0r = 0.f, u0i = 0.f, u1r = 0.f, u1i = 0.f;
#pragma unroll
            for (int n = 0; n < 16; ++n) {
                float2 ov = os[m * 16 + n];          // uniform -> broadcast
                float tr = ov.x * twr[n] - ov.y * twi[n];   // * e^{+i n w0}
                float ti2 = ov.x * twi[n] + ov.y * twr[n];
                u0r += tr; u0i += ti2;
                if (n & 1) { u1r -= tr; u1i -= ti2; }
                else       { u1r += tr; u1i += ti2; }
            }
            U[m][w0]       = make_float2(u0r, u0i);
            U[m][w0 + 128] = make_float2(u1r, u1i);
        }
    }
    __syncthreads();

    // stage 3: radix-4 inverse h-DFT: rows h, h+64, h+128, h+192 share one
    // U*R product via i^{mk} class accumulators. Lane owns w = 4l..4l+3.
    const int l = t & 63, wv = t >> 6;
    const int h0 = wv * 16;
    float Ur[4][16], Ui[4][16];
#pragma unroll
    for (int m = 0; m < 16; ++m) {
        const float4* Um = (const float4*)&U[m][0];
        float4 p0 = Um[2 * l], p1 = Um[2 * l + 1];
        Ur[0][m] = p0.x; Ui[0][m] = p0.y; Ur[1][m] = p0.z; Ui[1][m] = p0.w;
        Ur[2][m] = p1.x; Ui[2][m] = p1.y; Ur[3][m] = p1.z; Ui[3][m] = p1.w;
    }
    float Rr[16], Ri[16], Sr[16], Si[16];
#pragma unroll
    for (int m = 0; m < 16; ++m) {
        float2 i0 = tw[(m * h0) & 255];
        Rr[m] = i0.x; Ri[m] = i0.y;      // e^{+i m h0}
        float2 st = tw[m];
        Sr[m] = st.x; Si[m] = st.y;      // e^{+i m}
    }

    float* yp = y + (size_t)bo * 65536;
    const float inv = 1.0f / 65536.0f;
    for (int j = 0; j < 16; ++j) {
        const int h = h0 + j;
        float A0[4] = {0,0,0,0}, A1[4] = {0,0,0,0}, A2[4] = {0,0,0,0};
        float A3[4] = {0,0,0,0}, B1[4] = {0,0,0,0}, B3[4] = {0,0,0,0};
#pragma unroll
        for (int m = 0; m < 16; ++m) {
            const float cr = Rr[m], ci = Ri[m];
            if ((m & 3) == 0) {
#pragma unroll
                for (int c = 0; c < 4; ++c) {
                    A0[c] = fmaf(Ur[c][m], cr, A0[c]);   // += Re(U R)
                    A0[c] = fmaf(-Ui[c][m], ci, A0[c]);
                }
            } else if ((m & 3) == 2) {
#pragma unroll
                for (int c = 0; c < 4; ++c) {
                    A2[c] = fmaf(Ur[c][m], cr, A2[c]);
                    A2[c] = fmaf(-Ui[c][m], ci, A2[c]);
                }
            } else if ((m & 3) == 1) {
#pragma unroll
                for (int c = 0; c < 4; ++c) {
                    A1[c] = fmaf(Ur[c][m], cr, A1[c]);   // Re
                    A1[c] = fmaf(-Ui[c][m], ci, A1[c]);
                    B1[c] = fmaf(Ur[c][m], ci, B1[c]);   // Im
                    B1[c] = fmaf(Ui[c][m], cr, B1[c]);
                }
            } else {
#pragma unroll
                for (int c = 0; c < 4; ++c) {
                    A3[c] = fmaf(Ur[c][m], cr, A3[c]);
                    A3[c] = fmaf(-Ui[c][m], ci, A3[c]);
                    B3[c] = fmaf(Ur[c][m], ci, B3[c]);
                    B3[c] = fmaf(Ui[c][m], cr, B3[c]);
                }
            }
            Rr[m] = fmaf(cr, Sr[m], -ci * Si[m]);        // R *= S
            Ri[m] = fmaf(cr, Si[m],  ci * Sr[m]);
        }
        // y(h)      = A0+A1+A2+A3        y(h+64)  = A0-B1-A2+B3
        // y(h+128)  = A0-A1+A2-A3        y(h+192) = A0+B1-A2-B3
        float4 y0, y1, y2, y3;
        float* o0 = &y0.x; float* o1 = &y1.x; float* o2 = &y2.x; float* o3 = &y3.x;
#pragma unroll
        for (int c = 0; c < 4; ++c) {
            const float p = A0[c] + A2[c], q = A1[c] + A3[c];
            const float r = A0[c] - A2[c], s = B3[c] - B1[c];
            o0[c] = (p + q) * inv;
            o2[c] = (p - q) * inv;
            o1[c] = (r + s) * inv;
            o3[c] = (r - s) * inv;
        }
        ((float4*)(yp + h * 256))[l]         = y0;
        ((float4*)(yp + (h + 64) * 256))[l]  = y1;
        ((float4*)(yp + (h + 128) * 256))[l] = y2;
        ((float4*)(yp + (h + 192) * 256))[l] = y3;
    }
}

extern "C" void kernel_launch(void* const* d_in, const int* in_sizes, int n_in,
                              void* d_out, int out_size, void* d_ws, size_t ws_size,
                              hipStream_t stream) {
    const float* x  = (const float*)d_in[0];   // [16][32][256][256]
    const float* wr = (const float*)d_in[1];   // [32][32][16][16]
    const float* wi = (const float*)d_in[2];   // [32][32][16][16]
    float* y = (float*)d_out;                  // [16][32][256][256]

    float2* xsub = (float2*)d_ws;              // 512*256*8 = 1 MB

    kF<<<512, 256, 0, stream>>>(x, xsub);
    kI<<<512, 256, 0, stream>>>(xsub, wr, wi, y);
}